// Round 1
// baseline (570.823 us; speedup 1.0000x reference)
//
#include <hip/hip_runtime.h>
#include <hip/hip_bf16.h>

using bf16 = __hip_bfloat16;
typedef __attribute__((ext_vector_type(8))) short bf16x8;
typedef __attribute__((ext_vector_type(4))) float f32x4;

constexpr int BATCH = 4096;
constexpr int D_IN  = 1024;
constexpr int NEXP  = 16;
constexpr int EMB   = 256;
constexpr int H1    = 2048;
constexpr int H2    = 1024;
constexpr int OUTD  = 512;
constexpr int SLOTS = BATCH * 2;          // 8192 (token, expert) assignments
constexpr int SLOTS_PAD = SLOTS + 64;     // tile overrun pad
constexpr int MAX_TILES = SLOTS / 64 + NEXP;  // 144: sum ceil(n_e/64) bound

// ---- workspace layout (bytes) ----
constexpr size_t WS_XB     = 0;                                    // bf16 x [4096][1024]
constexpr size_t WS_H1     = WS_XB     + (size_t)BATCH * D_IN * 2; // bf16 [8256][2048]
constexpr size_t WS_H2     = WS_H1     + (size_t)SLOTS_PAD * H1 * 2;
constexpr size_t WS_OSL    = WS_H2     + (size_t)SLOTS_PAD * H2 * 2; // f32 [8256][512]
constexpr size_t WS_TOPI   = WS_OSL    + (size_t)SLOTS_PAD * OUTD * 4;
constexpr size_t WS_GATES  = WS_TOPI   + (size_t)SLOTS * 4;
constexpr size_t WS_SLOTOF = WS_GATES  + (size_t)SLOTS * 4;
constexpr size_t WS_TOKL   = WS_SLOTOF + (size_t)SLOTS * 4;
constexpr size_t WS_CNT    = WS_TOKL   + (size_t)SLOTS_PAD * 4;    // counts16|offsets16|cursors16
constexpr size_t WS_TMAP   = WS_CNT    + 64 * 4;                   // int2 [144]

__device__ __forceinline__ unsigned short f2bf(float f) {
    bf16 h = __float2bfloat16(f);
    return __builtin_bit_cast(unsigned short, h);
}

// ---------------- x -> bf16 ----------------
__global__ __launch_bounds__(256) void k_cvt_x(const float* __restrict__ x,
                                               unsigned short* __restrict__ xb) {
    int i = blockIdx.x * 256 + threadIdx.x;   // each handles 4 elems
    float4 v = reinterpret_cast<const float4*>(x)[i];
    ushort4 o;
    o.x = f2bf(v.x); o.y = f2bf(v.y); o.z = f2bf(v.z); o.w = f2bf(v.w);
    reinterpret_cast<ushort4*>(xb)[i] = o;
}

// ---------------- router GEMM: q = x @ Wr + br  (fp32, exactness matters) ----------------
__global__ __launch_bounds__(256) void k_router_gemm(const float* __restrict__ x,
                                                     const float* __restrict__ Wr,
                                                     const float* __restrict__ br,
                                                     float* __restrict__ qout) {
    __shared__ float As[64][17];
    __shared__ float Bs[16][68];
    int mb = blockIdx.x * 64, nb = blockIdx.y * 64;
    int t  = threadIdx.x;
    int tx = t & 15, ty = t >> 4;
    float acc[4][4] = {};
    int arow = t >> 2, ak = (t & 3) * 4;
    int bkr = t >> 4, bnc = (t & 15) * 4;
    for (int kt = 0; kt < D_IN; kt += 16) {
        float4 av = *reinterpret_cast<const float4*>(&x[(size_t)(mb + arow) * D_IN + kt + ak]);
        float4 bv = *reinterpret_cast<const float4*>(&Wr[(size_t)(kt + bkr) * EMB + nb + bnc]);
        As[arow][ak + 0] = av.x; As[arow][ak + 1] = av.y;
        As[arow][ak + 2] = av.z; As[arow][ak + 3] = av.w;
        Bs[bkr][bnc + 0] = bv.x; Bs[bkr][bnc + 1] = bv.y;
        Bs[bkr][bnc + 2] = bv.z; Bs[bkr][bnc + 3] = bv.w;
        __syncthreads();
#pragma unroll
        for (int k = 0; k < 16; k++) {
            float a[4], bb[4];
#pragma unroll
            for (int i = 0; i < 4; i++) a[i] = As[ty * 4 + i][k];
#pragma unroll
            for (int j = 0; j < 4; j++) bb[j] = Bs[k][tx * 4 + j];
#pragma unroll
            for (int i = 0; i < 4; i++)
#pragma unroll
                for (int j = 0; j < 4; j++) acc[i][j] = fmaf(a[i], bb[j], acc[i][j]);
        }
        __syncthreads();
    }
#pragma unroll
    for (int i = 0; i < 4; i++) {
        int row = mb + ty * 4 + i;
        float4 o;
        o.x = acc[i][0] + br[nb + tx * 4 + 0];
        o.y = acc[i][1] + br[nb + tx * 4 + 1];
        o.z = acc[i][2] + br[nb + tx * 4 + 2];
        o.w = acc[i][3] + br[nb + tx * 4 + 3];
        *reinterpret_cast<float4*>(&qout[(size_t)row * EMB + nb + tx * 4]) = o;
    }
}

// ---------------- distances, softmax, top-2 (one wave per example) ----------------
__global__ __launch_bounds__(256) void k_router_topk(const float* __restrict__ q,
                                                     const float* __restrict__ emb,
                                                     float* __restrict__ gp,
                                                     int* __restrict__ topi,
                                                     float* __restrict__ gates) {
    int b    = blockIdx.x * 4 + (threadIdx.x >> 6);
    int lane = threadIdx.x & 63;
    int e    = lane & 15;
    int seg  = (lane >> 4) * 64;
    const float* qr = q + (size_t)b * EMB + seg;
    const float* er = emb + (size_t)e * EMB + seg;
    float d2 = 0.f;
#pragma unroll 8
    for (int i = 0; i < 64; i++) { float d = qr[i] - er[i]; d2 = fmaf(d, d, d2); }
    d2 += __shfl_xor(d2, 16);
    d2 += __shfl_xor(d2, 32);
    float s = -d2;                       // every lane holds score for expert e = lane&15
    float m = s;
#pragma unroll
    for (int o = 1; o < 16; o <<= 1) m = fmaxf(m, __shfl_xor(m, o));
    float ex  = __expf(s - m);
    float sum = ex;
#pragma unroll
    for (int o = 1; o < 16; o <<= 1) sum += __shfl_xor(sum, o);
    if (lane < 16) gp[(size_t)b * NEXP + lane] = ex / sum;
    // top-1 (max, tie -> lower index)
    float v1 = s; int i1 = e;
#pragma unroll
    for (int o = 1; o < 16; o <<= 1) {
        float ov = __shfl_xor(v1, o); int oi = __shfl_xor(i1, o);
        if (ov > v1 || (ov == v1 && oi < i1)) { v1 = ov; i1 = oi; }
    }
    float s2 = (e == i1) ? -1e30f : s;
    float v2 = s2; int i2 = e;
#pragma unroll
    for (int o = 1; o < 16; o <<= 1) {
        float ov = __shfl_xor(v2, o); int oi = __shfl_xor(i2, o);
        if (ov > v2 || (ov == v2 && oi < i2)) { v2 = ov; i2 = oi; }
    }
    if (lane == 0) {
        topi[b * 2] = i1; topi[b * 2 + 1] = i2;
        float tv  = __expf(v2 - v1);
        float inv = 1.f / (1.f + tv);
        gates[b * 2] = inv; gates[b * 2 + 1] = tv * inv;
    }
}

// ---------------- routing bookkeeping ----------------
__global__ void k_zero(int* counts) { if (threadIdx.x < NEXP) counts[threadIdx.x] = 0; }

__global__ __launch_bounds__(256) void k_count(const int* __restrict__ topi, int* __restrict__ counts) {
    int i = blockIdx.x * 256 + threadIdx.x;
    atomicAdd(&counts[topi[i]], 1);
}

__global__ void k_scan(const int* __restrict__ counts, int* __restrict__ offsets,
                       int* __restrict__ cursors, int2* __restrict__ tilemap) {
    if (threadIdx.x != 0) return;
    int off = 0, nt = 0;
    for (int e = 0; e < NEXP; e++) {
        offsets[e] = off; cursors[e] = off;
        int c = counts[e];
        int ntile = (c + 63) >> 6;
        for (int i = 0; i < ntile; i++) { tilemap[nt] = make_int2(e, i); nt++; }
        off += c;
    }
    for (; nt < MAX_TILES; nt++) tilemap[nt] = make_int2(-1, 0);
}

__global__ __launch_bounds__(256) void k_scatter(const int* __restrict__ topi, int* __restrict__ cursors,
                                                 int* __restrict__ toklist, int* __restrict__ slotof) {
    int i = blockIdx.x * 256 + threadIdx.x;
    int e = topi[i];
    int s = atomicAdd(&cursors[e], 1);
    toklist[s] = i >> 1;
    slotof[i]  = s;
}

// ---------------- grouped expert GEMM ----------------
// MODE 0: gather x rows, relu -> bf16 h    (L1)
// MODE 1: contiguous h in, relu -> bf16 h  (L2)
// MODE 2: contiguous h in, fp32 out + bias (L3)
template <int KD, int ND, int MODE>
__global__ __launch_bounds__(256) void k_expert_gemm(
    const unsigned short* __restrict__ Xin, const float* __restrict__ Wg,
    const float* __restrict__ bg, unsigned short* __restrict__ Hout,
    float* __restrict__ Oout, const int* __restrict__ counts,
    const int* __restrict__ offsets, const int* __restrict__ toklist,
    const int2* __restrict__ tilemap) {
    int2 tm = tilemap[blockIdx.y];
    int e = tm.x;
    if (e < 0) return;
    int mt  = tm.y;
    int n_e = counts[e];
    if (mt * 64 >= n_e) return;  // (defensive; tilemap already exact)
    int off = offsets[e];
    int n0  = blockIdx.x * 64;

    __shared__ __align__(16) unsigned short Asl[64][72];
    __shared__ __align__(16) unsigned short Bsl[64][72];  // [n][k]

    int t  = threadIdx.x;
    int r0 = t >> 3;             // 0..31
    int c0 = (t & 7) * 8;        // bf16 elems within row
    int r1 = r0 + 32;
    const unsigned short* rowp0;
    const unsigned short* rowp1;
    if (MODE == 0) {
        int g0 = mt * 64 + r0, g1 = mt * 64 + r1;
        int tok0 = (g0 < n_e) ? toklist[off + g0] : 0;
        int tok1 = (g1 < n_e) ? toklist[off + g1] : 0;
        rowp0 = Xin + (size_t)tok0 * KD;
        rowp1 = Xin + (size_t)tok1 * KD;
    } else {
        rowp0 = Xin + (size_t)(off + mt * 64 + r0) * KD;
        rowp1 = Xin + (size_t)(off + mt * 64 + r1) * KD;
    }
    const float* Wbase = Wg + (size_t)e * KD * ND + n0;

    f32x4 acc[2][2];
#pragma unroll
    for (int mi = 0; mi < 2; mi++)
#pragma unroll
        for (int ni = 0; ni < 2; ni++) acc[mi][ni] = {0.f, 0.f, 0.f, 0.f};

    int wv = t >> 6;
    int wr = (wv >> 1) * 32;
    int wc = (wv & 1) * 32;
    int lane = t & 63;
    int lr = lane & 15;
    int lk = (lane >> 4) * 8;

    for (int kt = 0; kt < KD; kt += 64) {
        *reinterpret_cast<int4*>(&Asl[r0][c0]) = *reinterpret_cast<const int4*>(rowp0 + kt + c0);
        *reinterpret_cast<int4*>(&Asl[r1][c0]) = *reinterpret_cast<const int4*>(rowp1 + kt + c0);
#pragma unroll
        for (int j = 0; j < 4; j++) {
            int c  = t + j * 256;
            int kr = c >> 4;
            int nc = (c & 15) * 4;
            float4 v = *reinterpret_cast<const float4*>(Wbase + (size_t)(kt + kr) * ND + nc);
            Bsl[nc + 0][kr] = f2bf(v.x);
            Bsl[nc + 1][kr] = f2bf(v.y);
            Bsl[nc + 2][kr] = f2bf(v.z);
            Bsl[nc + 3][kr] = f2bf(v.w);
        }
        __syncthreads();
#pragma unroll
        for (int ks = 0; ks < 64; ks += 32) {
            bf16x8 a0 = *reinterpret_cast<const bf16x8*>(&Asl[wr + lr][ks + lk]);
            bf16x8 a1 = *reinterpret_cast<const bf16x8*>(&Asl[wr + 16 + lr][ks + lk]);
            bf16x8 b0 = *reinterpret_cast<const bf16x8*>(&Bsl[wc + lr][ks + lk]);
            bf16x8 b1 = *reinterpret_cast<const bf16x8*>(&Bsl[wc + 16 + lr][ks + lk]);
            acc[0][0] = __builtin_amdgcn_mfma_f32_16x16x32_bf16(a0, b0, acc[0][0], 0, 0, 0);
            acc[0][1] = __builtin_amdgcn_mfma_f32_16x16x32_bf16(a0, b1, acc[0][1], 0, 0, 0);
            acc[1][0] = __builtin_amdgcn_mfma_f32_16x16x32_bf16(a1, b0, acc[1][0], 0, 0, 0);
            acc[1][1] = __builtin_amdgcn_mfma_f32_16x16x32_bf16(a1, b1, acc[1][1], 0, 0, 0);
        }
        __syncthreads();
    }

    int rowbase = (lane >> 4) * 4;
#pragma unroll
    for (int ni = 0; ni < 2; ni++) {
        int col = n0 + wc + ni * 16 + lr;
        float bv = bg[(size_t)e * ND + col];
#pragma unroll
        for (int mi = 0; mi < 2; mi++) {
#pragma unroll
            for (int qi = 0; qi < 4; qi++) {
                int r = wr + mi * 16 + rowbase + qi;
                int g = mt * 64 + r;
                if (g < n_e) {
                    float v = acc[mi][ni][qi] + bv;
                    if (MODE == 2) {
                        Oout[(size_t)(off + g) * ND + col] = v;
                    } else {
                        v = fmaxf(v, 0.f);
                        Hout[(size_t)(off + g) * ND + col] = f2bf(v);
                    }
                }
            }
        }
    }
}

// ---------------- final combine (deterministic 2-term sum) ----------------
__global__ __launch_bounds__(128) void k_combine(const float* __restrict__ osl,
                                                 const float* __restrict__ gates,
                                                 const int* __restrict__ slotof,
                                                 float* __restrict__ outf) {
    int b = blockIdx.x;
    int j = threadIdx.x;
    int s0 = slotof[b * 2], s1 = slotof[b * 2 + 1];
    float g0 = gates[b * 2], g1 = gates[b * 2 + 1];
    float4 o0 = reinterpret_cast<const float4*>(osl + (size_t)s0 * OUTD)[j];
    float4 o1 = reinterpret_cast<const float4*>(osl + (size_t)s1 * OUTD)[j];
    float4 r;
    r.x = g0 * o0.x + g1 * o1.x;
    r.y = g0 * o0.y + g1 * o1.y;
    r.z = g0 * o0.z + g1 * o1.z;
    r.w = g0 * o0.w + g1 * o1.w;
    reinterpret_cast<float4*>(outf + (size_t)b * OUTD)[j] = r;
}

extern "C" void kernel_launch(void* const* d_in, const int* in_sizes, int n_in,
                              void* d_out, int out_size, void* d_ws, size_t ws_size,
                              hipStream_t stream) {
    const float* x   = (const float*)d_in[0];
    const float* Wr  = (const float*)d_in[1];
    const float* br  = (const float*)d_in[2];
    const float* emb = (const float*)d_in[3];
    const float* W1  = (const float*)d_in[4];
    const float* b1  = (const float*)d_in[5];
    const float* W2  = (const float*)d_in[6];
    const float* b2  = (const float*)d_in[7];
    const float* W3  = (const float*)d_in[8];
    const float* b3  = (const float*)d_in[9];

    float* out_final = (float*)d_out;
    float* out_q     = out_final + (size_t)BATCH * OUTD;
    float* out_gp    = out_q + (size_t)BATCH * EMB;

    char* ws = (char*)d_ws;
    unsigned short* xb  = (unsigned short*)(ws + WS_XB);
    unsigned short* h1  = (unsigned short*)(ws + WS_H1);
    unsigned short* h2  = (unsigned short*)(ws + WS_H2);
    float* osl    = (float*)(ws + WS_OSL);
    int*   topi   = (int*)(ws + WS_TOPI);
    float* gates  = (float*)(ws + WS_GATES);
    int*   slotof = (int*)(ws + WS_SLOTOF);
    int*   toklist= (int*)(ws + WS_TOKL);
    int*   counts = (int*)(ws + WS_CNT);
    int*   offsets= counts + 16;
    int*   cursors= counts + 32;
    int2*  tilemap= (int2*)(ws + WS_TMAP);

    k_cvt_x<<<BATCH * D_IN / 4 / 256, 256, 0, stream>>>(x, xb);
    k_router_gemm<<<dim3(BATCH / 64, EMB / 64), 256, 0, stream>>>(x, Wr, br, out_q);
    k_router_topk<<<BATCH / 4, 256, 0, stream>>>(out_q, emb, out_gp, topi, gates);
    k_zero<<<1, 64, 0, stream>>>(counts);
    k_count<<<SLOTS / 256, 256, 0, stream>>>(topi, counts);
    k_scan<<<1, 64, 0, stream>>>(counts, offsets, cursors, tilemap);
    k_scatter<<<SLOTS / 256, 256, 0, stream>>>(topi, cursors, toklist, slotof);
    k_expert_gemm<D_IN, H1, 0><<<dim3(H1 / 64, MAX_TILES), 256, 0, stream>>>(
        xb, W1, b1, h1, nullptr, counts, offsets, toklist, tilemap);
    k_expert_gemm<H1, H2, 1><<<dim3(H2 / 64, MAX_TILES), 256, 0, stream>>>(
        h1, W2, b2, h2, nullptr, counts, offsets, toklist, tilemap);
    k_expert_gemm<H2, OUTD, 2><<<dim3(OUTD / 64, MAX_TILES), 256, 0, stream>>>(
        h2, W3, b3, nullptr, osl, counts, offsets, toklist, tilemap);
    k_combine<<<BATCH, 128, 0, stream>>>(osl, gates, slotof, out_final);
}

// Round 2
// 430.372 us; speedup vs baseline: 1.3263x; 1.3263x over previous
//
#include <hip/hip_runtime.h>
#include <hip/hip_bf16.h>

using bf16 = __hip_bfloat16;
typedef __attribute__((ext_vector_type(8))) short bf16x8;
typedef __attribute__((ext_vector_type(8))) unsigned short u16x8;
typedef __attribute__((ext_vector_type(4))) float f32x4;

constexpr int BATCH = 4096;
constexpr int D_IN  = 1024;
constexpr int NEXP  = 16;
constexpr int EMB   = 256;
constexpr int H1    = 2048;
constexpr int H2    = 1024;
constexpr int OUTD  = 512;
constexpr int SLOTS = BATCH * 2;              // 8192 (token, expert) assignments
constexpr int SLOTS_PAD = SLOTS + 128;        // 128-row tile overrun pad
constexpr int MAX_TILES = SLOTS / 128 + NEXP; // 80: sum ceil(n_e/128) bound

// ---- workspace layout (bytes) ----
constexpr size_t WS_XB     = 0;                                    // bf16 x [4096][1024]
constexpr size_t WS_H1     = WS_XB     + (size_t)BATCH * D_IN * 2; // bf16 [8320][2048]
constexpr size_t WS_H2     = WS_H1     + (size_t)SLOTS_PAD * H1 * 2;
constexpr size_t WS_OSL    = WS_H2     + (size_t)SLOTS_PAD * H2 * 2; // f32 [8320][512]
constexpr size_t WS_TOPI   = WS_OSL    + (size_t)SLOTS_PAD * OUTD * 4;
constexpr size_t WS_GATES  = WS_TOPI   + (size_t)SLOTS * 4;
constexpr size_t WS_SLOTOF = WS_GATES  + (size_t)SLOTS * 4;
constexpr size_t WS_TOKL   = WS_SLOTOF + (size_t)SLOTS * 4;
constexpr size_t WS_CNT    = WS_TOKL   + (size_t)SLOTS_PAD * 4;    // counts16|offsets16|cursors16
constexpr size_t WS_TMAP   = WS_CNT    + 64 * 4;                   // int2 [80]
constexpr size_t WS_WT     = ((WS_TMAP + (size_t)MAX_TILES * 8) + 255) & ~(size_t)255;
// Wt: one layer at a time, max 16*2048*1024 bf16 = 64 MB

__device__ __forceinline__ unsigned short f2bf(float f) {
    bf16 h = __float2bfloat16(f);
    return __builtin_bit_cast(unsigned short, h);
}

__device__ __forceinline__ void gload16(const unsigned short* g, unsigned short* l) {
    __builtin_amdgcn_global_load_lds(
        (const __attribute__((address_space(1))) unsigned int*)g,
        (__attribute__((address_space(3))) unsigned int*)l, 16, 0, 0);
}

// ---------------- x -> bf16 ----------------
__global__ __launch_bounds__(256) void k_cvt_x(const float* __restrict__ x,
                                               unsigned short* __restrict__ xb) {
    int i = blockIdx.x * 256 + threadIdx.x;
    float4 v = reinterpret_cast<const float4*>(x)[i];
    ushort4 o;
    o.x = f2bf(v.x); o.y = f2bf(v.y); o.z = f2bf(v.z); o.w = f2bf(v.w);
    reinterpret_cast<ushort4*>(xb)[i] = o;
}

// ---------------- weight transpose+convert: W[e][k][n] f32 -> Wt[e][n][k] bf16 ----------------
__global__ __launch_bounds__(256) void k_wtrans(const float* __restrict__ W,
                                                unsigned short* __restrict__ Wt,
                                                int KD, int ND) {
    __shared__ float Tf[64][65];
    int e = blockIdx.z;
    int n0 = blockIdx.x * 64, k0 = blockIdx.y * 64;
    const float* Wb = W + ((size_t)e * KD + k0) * ND + n0;
    int t  = threadIdx.x;
    int kr = t >> 4, c4 = (t & 15) * 4;
#pragma unroll
    for (int i = 0; i < 4; i++) {
        float4 v = *reinterpret_cast<const float4*>(Wb + (size_t)(kr + i * 16) * ND + c4);
        Tf[kr + i * 16][c4 + 0] = v.x; Tf[kr + i * 16][c4 + 1] = v.y;
        Tf[kr + i * 16][c4 + 2] = v.z; Tf[kr + i * 16][c4 + 3] = v.w;
    }
    __syncthreads();
    unsigned short* Wtb = Wt + ((size_t)e * ND + n0) * KD + k0;
#pragma unroll
    for (int i = 0; i < 2; i++) {
        int idx = t + i * 256;
        int n = idx >> 3, ck = (idx & 7) * 8;
        u16x8 o;
#pragma unroll
        for (int j = 0; j < 8; j++) o[j] = f2bf(Tf[ck + j][n]);
        *reinterpret_cast<u16x8*>(Wtb + (size_t)n * KD + ck) = o;
    }
}

// ---------------- router GEMM: q = x @ Wr + br  (fp32, exactness matters) ----------------
__global__ __launch_bounds__(256) void k_router_gemm(const float* __restrict__ x,
                                                     const float* __restrict__ Wr,
                                                     const float* __restrict__ br,
                                                     float* __restrict__ qout) {
    __shared__ float As[64][17];
    __shared__ float Bs[16][68];
    int mb = blockIdx.x * 64, nb = blockIdx.y * 64;
    int t  = threadIdx.x;
    int tx = t & 15, ty = t >> 4;
    float acc[4][4] = {};
    int arow = t >> 2, ak = (t & 3) * 4;
    int bkr = t >> 4, bnc = (t & 15) * 4;
    for (int kt = 0; kt < D_IN; kt += 16) {
        float4 av = *reinterpret_cast<const float4*>(&x[(size_t)(mb + arow) * D_IN + kt + ak]);
        float4 bv = *reinterpret_cast<const float4*>(&Wr[(size_t)(kt + bkr) * EMB + nb + bnc]);
        As[arow][ak + 0] = av.x; As[arow][ak + 1] = av.y;
        As[arow][ak + 2] = av.z; As[arow][ak + 3] = av.w;
        Bs[bkr][bnc + 0] = bv.x; Bs[bkr][bnc + 1] = bv.y;
        Bs[bkr][bnc + 2] = bv.z; Bs[bkr][bnc + 3] = bv.w;
        __syncthreads();
#pragma unroll
        for (int k = 0; k < 16; k++) {
            float a[4], bb[4];
#pragma unroll
            for (int i = 0; i < 4; i++) a[i] = As[ty * 4 + i][k];
#pragma unroll
            for (int j = 0; j < 4; j++) bb[j] = Bs[k][tx * 4 + j];
#pragma unroll
            for (int i = 0; i < 4; i++)
#pragma unroll
                for (int j = 0; j < 4; j++) acc[i][j] = fmaf(a[i], bb[j], acc[i][j]);
        }
        __syncthreads();
    }
#pragma unroll
    for (int i = 0; i < 4; i++) {
        int row = mb + ty * 4 + i;
        float4 o;
        o.x = acc[i][0] + br[nb + tx * 4 + 0];
        o.y = acc[i][1] + br[nb + tx * 4 + 1];
        o.z = acc[i][2] + br[nb + tx * 4 + 2];
        o.w = acc[i][3] + br[nb + tx * 4 + 3];
        *reinterpret_cast<float4*>(&qout[(size_t)row * EMB + nb + tx * 4]) = o;
    }
}

// ---------------- distances, softmax, top-2 (one wave per example) ----------------
__global__ __launch_bounds__(256) void k_router_topk(const float* __restrict__ q,
                                                     const float* __restrict__ emb,
                                                     float* __restrict__ gp,
                                                     int* __restrict__ topi,
                                                     float* __restrict__ gates) {
    int b    = blockIdx.x * 4 + (threadIdx.x >> 6);
    int lane = threadIdx.x & 63;
    int e    = lane & 15;
    int seg  = (lane >> 4) * 64;
    const float* qr = q + (size_t)b * EMB + seg;
    const float* er = emb + (size_t)e * EMB + seg;
    float d2 = 0.f;
#pragma unroll 8
    for (int i = 0; i < 64; i++) { float d = qr[i] - er[i]; d2 = fmaf(d, d, d2); }
    d2 += __shfl_xor(d2, 16);
    d2 += __shfl_xor(d2, 32);
    float s = -d2;
    float m = s;
#pragma unroll
    for (int o = 1; o < 16; o <<= 1) m = fmaxf(m, __shfl_xor(m, o));
    float ex  = __expf(s - m);
    float sum = ex;
#pragma unroll
    for (int o = 1; o < 16; o <<= 1) sum += __shfl_xor(sum, o);
    if (lane < 16) gp[(size_t)b * NEXP + lane] = ex / sum;
    float v1 = s; int i1 = e;
#pragma unroll
    for (int o = 1; o < 16; o <<= 1) {
        float ov = __shfl_xor(v1, o); int oi = __shfl_xor(i1, o);
        if (ov > v1 || (ov == v1 && oi < i1)) { v1 = ov; i1 = oi; }
    }
    float s2 = (e == i1) ? -1e30f : s;
    float v2 = s2; int i2 = e;
#pragma unroll
    for (int o = 1; o < 16; o <<= 1) {
        float ov = __shfl_xor(v2, o); int oi = __shfl_xor(i2, o);
        if (ov > v2 || (ov == v2 && oi < i2)) { v2 = ov; i2 = oi; }
    }
    if (lane == 0) {
        topi[b * 2] = i1; topi[b * 2 + 1] = i2;
        float tv  = __expf(v2 - v1);
        float inv = 1.f / (1.f + tv);
        gates[b * 2] = inv; gates[b * 2 + 1] = tv * inv;
    }
}

// ---------------- routing bookkeeping ----------------
__global__ void k_zero(int* counts) { if (threadIdx.x < NEXP) counts[threadIdx.x] = 0; }

__global__ __launch_bounds__(256) void k_count(const int* __restrict__ topi, int* __restrict__ counts) {
    int i = blockIdx.x * 256 + threadIdx.x;
    atomicAdd(&counts[topi[i]], 1);
}

__global__ void k_scan(const int* __restrict__ counts, int* __restrict__ offsets,
                       int* __restrict__ cursors, int2* __restrict__ tilemap) {
    if (threadIdx.x != 0) return;
    int off = 0, nt = 0;
    for (int e = 0; e < NEXP; e++) {
        offsets[e] = off; cursors[e] = off;
        int c = counts[e];
        int ntile = (c + 127) >> 7;
        for (int i = 0; i < ntile; i++) { tilemap[nt] = make_int2(e, i); nt++; }
        off += c;
    }
    for (; nt < MAX_TILES; nt++) tilemap[nt] = make_int2(-1, 0);
}

__global__ __launch_bounds__(256) void k_scatter(const int* __restrict__ topi, int* __restrict__ cursors,
                                                 int* __restrict__ toklist, int* __restrict__ slotof) {
    int i = blockIdx.x * 256 + threadIdx.x;
    int e = topi[i];
    int s = atomicAdd(&cursors[e], 1);
    toklist[s] = i >> 1;
    slotof[i]  = s;
}

// ---------------- grouped expert GEMM, m97 structure ----------------
// 128x128 tile, BK=64, 4 waves each owning a 64x64 sub-tile (4x4 16x16x32 frags).
// A and B staged via global_load_lds width=16, linear LDS dest, XOR-swizzled
// SOURCE chunk + matching swizzled ds_read (rule #21: both-sides involution).
// MODE 0: gather x rows, relu -> bf16 h    (L1)
// MODE 1: contiguous h in, relu -> bf16 h  (L2)
// MODE 2: contiguous h in, fp32 out + bias (L3)
template <int KD, int ND, int MODE>
__global__ __launch_bounds__(256) void k_expert_gemm(
    const unsigned short* __restrict__ Xin, const unsigned short* __restrict__ Wt,
    const float* __restrict__ bg, unsigned short* __restrict__ Hout,
    float* __restrict__ Oout, const int* __restrict__ counts,
    const int* __restrict__ offsets, const int* __restrict__ toklist,
    const int2* __restrict__ tilemap) {
    int2 tm = tilemap[blockIdx.y];
    int e = tm.x;
    if (e < 0) return;
    int mt  = tm.y;
    int n_e = counts[e];
    if (mt * 128 >= n_e) return;
    int off = offsets[e];
    int n0  = blockIdx.x * 128;

    // [row][64 k] bf16, linear (global_load_lds requires contiguous dest)
    __shared__ __align__(16) unsigned short As[128 * 64];
    __shared__ __align__(16) unsigned short Bs[128 * 64];

    int t    = threadIdx.x;
    int lane = t & 63;
    int w    = t >> 6;
    int wr   = (w >> 1) * 64;   // wave row origin
    int wc   = (w & 1) * 64;    // wave col origin

    // staging geometry: issue i covers rows i*32 + w*8 + (lane>>3); chunk = lane&7
    int srow = lane >> 3;
    int swz  = (lane & 7) ^ srow;   // source chunk, swizzled (row&7 == srow for every issue)
    const unsigned short* asrc[4];
    const unsigned short* bsrc[4];
#pragma unroll
    for (int i = 0; i < 4; i++) {
        int r = i * 32 + w * 8 + srow;
        int g = mt * 128 + r;
        size_t arow;
        if (MODE == 0) {
            int gg = (g < n_e) ? g : (n_e - 1);
            arow = (size_t)toklist[off + gg];
        } else {
            arow = (size_t)(off + g);   // may bleed into pad/next expert; masked at store
        }
        asrc[i] = Xin + arow * KD + swz * 8;
        bsrc[i] = Wt + ((size_t)e * ND + n0 + r) * KD + swz * 8;
    }

    f32x4 acc[4][4];
#pragma unroll
    for (int mi = 0; mi < 4; mi++)
#pragma unroll
        for (int ni = 0; ni < 4; ni++) acc[mi][ni] = {0.f, 0.f, 0.f, 0.f};

    int lr  = lane & 15;
    int lkc = lane >> 4;          // 0..3: which 16B chunk of the 32-elem k-slice

    for (int kt = 0; kt < KD; kt += 64) {
#pragma unroll
        for (int i = 0; i < 4; i++) {
            gload16(asrc[i] + kt, (unsigned short*)((char*)As + (i * 32 + w * 8) * 128) + lane * 8);
            gload16(bsrc[i] + kt, (unsigned short*)((char*)Bs + (i * 32 + w * 8) * 128) + lane * 8);
        }
        __syncthreads();
#pragma unroll
        for (int ks = 0; ks < 2; ks++) {
            bf16x8 a[4], b[4];
#pragma unroll
            for (int mi = 0; mi < 4; mi++) {
                int row = wr + mi * 16 + lr;
                int c   = (lkc + ks * 4) ^ (row & 7);
                a[mi] = *reinterpret_cast<const bf16x8*>((char*)As + row * 128 + c * 16);
            }
#pragma unroll
            for (int ni = 0; ni < 4; ni++) {
                int row = wc + ni * 16 + lr;
                int c   = (lkc + ks * 4) ^ (row & 7);
                b[ni] = *reinterpret_cast<const bf16x8*>((char*)Bs + row * 128 + c * 16);
            }
#pragma unroll
            for (int mi = 0; mi < 4; mi++)
#pragma unroll
                for (int ni = 0; ni < 4; ni++)
                    acc[mi][ni] = __builtin_amdgcn_mfma_f32_16x16x32_bf16(a[mi], b[ni], acc[mi][ni], 0, 0, 0);
        }
        __syncthreads();
    }

    // epilogue: C/D map col=lane&15, row=(lane>>4)*4+reg
    int rowbase = (lane >> 4) * 4;
#pragma unroll
    for (int ni = 0; ni < 4; ni++) {
        int col = n0 + wc + ni * 16 + lr;
        float bv = bg[(size_t)e * ND + col];
#pragma unroll
        for (int mi = 0; mi < 4; mi++) {
#pragma unroll
            for (int qi = 0; qi < 4; qi++) {
                int g = mt * 128 + wr + mi * 16 + rowbase + qi;
                if (g < n_e) {
                    float v = acc[mi][ni][qi] + bv;
                    if (MODE == 2) {
                        Oout[(size_t)(off + g) * ND + col] = v;
                    } else {
                        v = fmaxf(v, 0.f);
                        Hout[(size_t)(off + g) * ND + col] = f2bf(v);
                    }
                }
            }
        }
    }
}

// ---------------- final combine (deterministic 2-term sum) ----------------
__global__ __launch_bounds__(128) void k_combine(const float* __restrict__ osl,
                                                 const float* __restrict__ gates,
                                                 const int* __restrict__ slotof,
                                                 float* __restrict__ outf) {
    int b = blockIdx.x;
    int j = threadIdx.x;
    int s0 = slotof[b * 2], s1 = slotof[b * 2 + 1];
    float g0 = gates[b * 2], g1 = gates[b * 2 + 1];
    float4 o0 = reinterpret_cast<const float4*>(osl + (size_t)s0 * OUTD)[j];
    float4 o1 = reinterpret_cast<const float4*>(osl + (size_t)s1 * OUTD)[j];
    float4 r;
    r.x = g0 * o0.x + g1 * o1.x;
    r.y = g0 * o0.y + g1 * o1.y;
    r.z = g0 * o0.z + g1 * o1.z;
    r.w = g0 * o0.w + g1 * o1.w;
    reinterpret_cast<float4*>(outf + (size_t)b * OUTD)[j] = r;
}

extern "C" void kernel_launch(void* const* d_in, const int* in_sizes, int n_in,
                              void* d_out, int out_size, void* d_ws, size_t ws_size,
                              hipStream_t stream) {
    const float* x   = (const float*)d_in[0];
    const float* Wr  = (const float*)d_in[1];
    const float* br  = (const float*)d_in[2];
    const float* emb = (const float*)d_in[3];
    const float* W1  = (const float*)d_in[4];
    const float* b1  = (const float*)d_in[5];
    const float* W2  = (const float*)d_in[6];
    const float* b2  = (const float*)d_in[7];
    const float* W3  = (const float*)d_in[8];
    const float* b3  = (const float*)d_in[9];

    float* out_final = (float*)d_out;
    float* out_q     = out_final + (size_t)BATCH * OUTD;
    float* out_gp    = out_q + (size_t)BATCH * EMB;

    char* ws = (char*)d_ws;
    unsigned short* xb  = (unsigned short*)(ws + WS_XB);
    unsigned short* h1  = (unsigned short*)(ws + WS_H1);
    unsigned short* h2  = (unsigned short*)(ws + WS_H2);
    float* osl    = (float*)(ws + WS_OSL);
    int*   topi   = (int*)(ws + WS_TOPI);
    float* gates  = (float*)(ws + WS_GATES);
    int*   slotof = (int*)(ws + WS_SLOTOF);
    int*   toklist= (int*)(ws + WS_TOKL);
    int*   counts = (int*)(ws + WS_CNT);
    int*   offsets= counts + 16;
    int*   cursors= counts + 32;
    int2*  tilemap= (int2*)(ws + WS_TMAP);
    unsigned short* wt = (unsigned short*)(ws + WS_WT);

    k_cvt_x<<<BATCH * D_IN / 4 / 256, 256, 0, stream>>>(x, xb);
    k_router_gemm<<<dim3(BATCH / 64, EMB / 64), 256, 0, stream>>>(x, Wr, br, out_q);
    k_router_topk<<<BATCH / 4, 256, 0, stream>>>(out_q, emb, out_gp, topi, gates);
    k_zero<<<1, 64, 0, stream>>>(counts);
    k_count<<<SLOTS / 256, 256, 0, stream>>>(topi, counts);
    k_scan<<<1, 64, 0, stream>>>(counts, offsets, cursors, tilemap);
    k_scatter<<<SLOTS / 256, 256, 0, stream>>>(topi, cursors, toklist, slotof);

    k_wtrans<<<dim3(H1 / 64, D_IN / 64, NEXP), 256, 0, stream>>>(W1, wt, D_IN, H1);
    k_expert_gemm<D_IN, H1, 0><<<dim3(H1 / 128, MAX_TILES), 256, 0, stream>>>(
        xb, wt, b1, h1, nullptr, counts, offsets, toklist, tilemap);

    k_wtrans<<<dim3(H2 / 64, H1 / 64, NEXP), 256, 0, stream>>>(W2, wt, H1, H2);
    k_expert_gemm<H1, H2, 1><<<dim3(H2 / 128, MAX_TILES), 256, 0, stream>>>(
        h1, wt, b2, h2, nullptr, counts, offsets, toklist, tilemap);

    k_wtrans<<<dim3(OUTD / 64, H2 / 64, NEXP), 256, 0, stream>>>(W3, wt, H2, OUTD);
    k_expert_gemm<H2, OUTD, 2><<<dim3(OUTD / 128, MAX_TILES), 256, 0, stream>>>(
        h2, wt, b3, nullptr, osl, counts, offsets, toklist, tilemap);

    k_combine<<<BATCH, 128, 0, stream>>>(osl, gates, slotof, out_final);
}

// Round 3
// 415.561 us; speedup vs baseline: 1.3736x; 1.0356x over previous
//
#include <hip/hip_runtime.h>
#include <hip/hip_bf16.h>

using bf16 = __hip_bfloat16;
typedef __attribute__((ext_vector_type(8))) short bf16x8;
typedef __attribute__((ext_vector_type(8))) unsigned short u16x8;
typedef __attribute__((ext_vector_type(4))) float f32x4;

constexpr int BATCH = 4096;
constexpr int D_IN  = 1024;
constexpr int NEXP  = 16;
constexpr int EMB   = 256;
constexpr int H1    = 2048;
constexpr int H2    = 1024;
constexpr int OUTD  = 512;
constexpr int SLOTS = BATCH * 2;              // 8192 (token, expert) assignments
constexpr int SLOTS_PAD = SLOTS + 128;        // 128-row tile overrun pad
constexpr int MAX_TILES = SLOTS / 128 + NEXP; // 80: sum ceil(n_e/128) bound; 8 XCD bins x 10
constexpr int BIN_CAP   = MAX_TILES / 8;      // 10 tiles per XCD bin

// ---- workspace layout (bytes) ----
constexpr size_t WS_XB     = 0;                                    // bf16 x [4096][1024]
constexpr size_t WS_H1     = WS_XB     + (size_t)BATCH * D_IN * 2; // bf16 [8320][2048]
constexpr size_t WS_H2     = WS_H1     + (size_t)SLOTS_PAD * H1 * 2;
constexpr size_t WS_OSL    = WS_H2     + (size_t)SLOTS_PAD * H2 * 2; // f32 [8320][512]
constexpr size_t WS_TOPI   = WS_OSL    + (size_t)SLOTS_PAD * OUTD * 4;
constexpr size_t WS_GATES  = WS_TOPI   + (size_t)SLOTS * 4;
constexpr size_t WS_SLOTOF = WS_GATES  + (size_t)SLOTS * 4;
constexpr size_t WS_TOKL   = WS_SLOTOF + (size_t)SLOTS * 4;
constexpr size_t WS_CNT    = WS_TOKL   + (size_t)SLOTS_PAD * 4;    // counts16|offsets16|cursors16
constexpr size_t WS_TMAP   = WS_CNT    + 64 * 4;                   // int2 [80]
constexpr size_t WS_WT     = ((WS_TMAP + (size_t)MAX_TILES * 8) + 255) & ~(size_t)255;
// Wt: one layer at a time, max 16*2048*1024 bf16 = 64 MB

__device__ __forceinline__ unsigned short f2bf(float f) {
    bf16 h = __float2bfloat16(f);
    return __builtin_bit_cast(unsigned short, h);
}

__device__ __forceinline__ void gload16(const unsigned short* g, unsigned short* l) {
    __builtin_amdgcn_global_load_lds(
        (const __attribute__((address_space(1))) unsigned int*)g,
        (__attribute__((address_space(3))) unsigned int*)l, 16, 0, 0);
}

// ---------------- x -> bf16 ----------------
__global__ __launch_bounds__(256) void k_cvt_x(const float* __restrict__ x,
                                               unsigned short* __restrict__ xb) {
    int i = blockIdx.x * 256 + threadIdx.x;
    float4 v = reinterpret_cast<const float4*>(x)[i];
    ushort4 o;
    o.x = f2bf(v.x); o.y = f2bf(v.y); o.z = f2bf(v.z); o.w = f2bf(v.w);
    reinterpret_cast<ushort4*>(xb)[i] = o;
}

// ---------------- weight transpose+convert: W[e][k][n] f32 -> Wt[e][n][k] bf16 ----------------
__global__ __launch_bounds__(256) void k_wtrans(const float* __restrict__ W,
                                                unsigned short* __restrict__ Wt,
                                                int KD, int ND) {
    __shared__ float Tf[64][65];
    int e = blockIdx.z;
    int n0 = blockIdx.x * 64, k0 = blockIdx.y * 64;
    const float* Wb = W + ((size_t)e * KD + k0) * ND + n0;
    int t  = threadIdx.x;
    int kr = t >> 4, c4 = (t & 15) * 4;
#pragma unroll
    for (int i = 0; i < 4; i++) {
        float4 v = *reinterpret_cast<const float4*>(Wb + (size_t)(kr + i * 16) * ND + c4);
        Tf[kr + i * 16][c4 + 0] = v.x; Tf[kr + i * 16][c4 + 1] = v.y;
        Tf[kr + i * 16][c4 + 2] = v.z; Tf[kr + i * 16][c4 + 3] = v.w;
    }
    __syncthreads();
    unsigned short* Wtb = Wt + ((size_t)e * ND + n0) * KD + k0;
#pragma unroll
    for (int i = 0; i < 2; i++) {
        int idx = t + i * 256;
        int n = idx >> 3, ck = (idx & 7) * 8;
        u16x8 o;
#pragma unroll
        for (int j = 0; j < 8; j++) o[j] = f2bf(Tf[ck + j][n]);
        *reinterpret_cast<u16x8*>(Wtb + (size_t)n * KD + ck) = o;
    }
}

// ---------------- router GEMM: q = x @ Wr + br  (fp32, exactness matters) ----------------
__global__ __launch_bounds__(256) void k_router_gemm(const float* __restrict__ x,
                                                     const float* __restrict__ Wr,
                                                     const float* __restrict__ br,
                                                     float* __restrict__ qout) {
    __shared__ float As[64][17];
    __shared__ float Bs[16][68];
    int mb = blockIdx.x * 64, nb = blockIdx.y * 64;
    int t  = threadIdx.x;
    int tx = t & 15, ty = t >> 4;
    float acc[4][4] = {};
    int arow = t >> 2, ak = (t & 3) * 4;
    int bkr = t >> 4, bnc = (t & 15) * 4;
    for (int kt = 0; kt < D_IN; kt += 16) {
        float4 av = *reinterpret_cast<const float4*>(&x[(size_t)(mb + arow) * D_IN + kt + ak]);
        float4 bv = *reinterpret_cast<const float4*>(&Wr[(size_t)(kt + bkr) * EMB + nb + bnc]);
        As[arow][ak + 0] = av.x; As[arow][ak + 1] = av.y;
        As[arow][ak + 2] = av.z; As[arow][ak + 3] = av.w;
        Bs[bkr][bnc + 0] = bv.x; Bs[bkr][bnc + 1] = bv.y;
        Bs[bkr][bnc + 2] = bv.z; Bs[bkr][bnc + 3] = bv.w;
        __syncthreads();
#pragma unroll
        for (int k = 0; k < 16; k++) {
            float a[4], bb[4];
#pragma unroll
            for (int i = 0; i < 4; i++) a[i] = As[ty * 4 + i][k];
#pragma unroll
            for (int j = 0; j < 4; j++) bb[j] = Bs[k][tx * 4 + j];
#pragma unroll
            for (int i = 0; i < 4; i++)
#pragma unroll
                for (int j = 0; j < 4; j++) acc[i][j] = fmaf(a[i], bb[j], acc[i][j]);
        }
        __syncthreads();
    }
#pragma unroll
    for (int i = 0; i < 4; i++) {
        int row = mb + ty * 4 + i;
        float4 o;
        o.x = acc[i][0] + br[nb + tx * 4 + 0];
        o.y = acc[i][1] + br[nb + tx * 4 + 1];
        o.z = acc[i][2] + br[nb + tx * 4 + 2];
        o.w = acc[i][3] + br[nb + tx * 4 + 3];
        *reinterpret_cast<float4*>(&qout[(size_t)row * EMB + nb + tx * 4]) = o;
    }
}

// ---------------- distances, softmax, top-2 (one wave per example) ----------------
__global__ __launch_bounds__(256) void k_router_topk(const float* __restrict__ q,
                                                     const float* __restrict__ emb,
                                                     float* __restrict__ gp,
                                                     int* __restrict__ topi,
                                                     float* __restrict__ gates) {
    int b    = blockIdx.x * 4 + (threadIdx.x >> 6);
    int lane = threadIdx.x & 63;
    int e    = lane & 15;
    int seg  = (lane >> 4) * 64;
    const float* qr = q + (size_t)b * EMB + seg;
    const float* er = emb + (size_t)e * EMB + seg;
    float d2 = 0.f;
#pragma unroll 8
    for (int i = 0; i < 64; i++) { float d = qr[i] - er[i]; d2 = fmaf(d, d, d2); }
    d2 += __shfl_xor(d2, 16);
    d2 += __shfl_xor(d2, 32);
    float s = -d2;
    float m = s;
#pragma unroll
    for (int o = 1; o < 16; o <<= 1) m = fmaxf(m, __shfl_xor(m, o));
    float ex  = __expf(s - m);
    float sum = ex;
#pragma unroll
    for (int o = 1; o < 16; o <<= 1) sum += __shfl_xor(sum, o);
    if (lane < 16) gp[(size_t)b * NEXP + lane] = ex / sum;
    float v1 = s; int i1 = e;
#pragma unroll
    for (int o = 1; o < 16; o <<= 1) {
        float ov = __shfl_xor(v1, o); int oi = __shfl_xor(i1, o);
        if (ov > v1 || (ov == v1 && oi < i1)) { v1 = ov; i1 = oi; }
    }
    float s2 = (e == i1) ? -1e30f : s;
    float v2 = s2; int i2 = e;
#pragma unroll
    for (int o = 1; o < 16; o <<= 1) {
        float ov = __shfl_xor(v2, o); int oi = __shfl_xor(i2, o);
        if (ov > v2 || (ov == v2 && oi < i2)) { v2 = ov; i2 = oi; }
    }
    if (lane == 0) {
        topi[b * 2] = i1; topi[b * 2 + 1] = i2;
        float tv  = __expf(v2 - v1);
        float inv = 1.f / (1.f + tv);
        gates[b * 2] = inv; gates[b * 2 + 1] = tv * inv;
    }
}

// ---------------- routing bookkeeping ----------------
__global__ void k_zero(int* counts) { if (threadIdx.x < NEXP) counts[threadIdx.x] = 0; }

__global__ __launch_bounds__(256) void k_count(const int* __restrict__ topi, int* __restrict__ counts) {
    int i = blockIdx.x * 256 + threadIdx.x;
    atomicAdd(&counts[topi[i]], 1);
}

// Greedy bin-packing of expert tiles into 8 XCD bins of BIN_CAP:
// keeps each expert's tiles (B-panel reuse) and each m-tile's n-blocks
// (A-tile reuse) on one XCD L2, while balancing live tiles across XCDs.
__global__ void k_scan(const int* __restrict__ counts, int* __restrict__ offsets,
                       int* __restrict__ cursors, int2* __restrict__ tilemap) {
    if (threadIdx.x != 0) return;
    int off = 0;
    int nt_e[NEXP];
    for (int e = 0; e < NEXP; e++) {
        offsets[e] = off; cursors[e] = off;
        nt_e[e] = (counts[e] + 127) >> 7;
        off += counts[e];
    }
    for (int i = 0; i < MAX_TILES; i++) tilemap[i] = make_int2(-1, 0);
    int binload[8] = {0, 0, 0, 0, 0, 0, 0, 0};
    for (int e = 0; e < NEXP; e++) {
        int rem = nt_e[e], ti = 0;
        while (rem > 0) {
            int b = 0;
            for (int q = 1; q < 8; q++)
                if (binload[q] < binload[b]) b = q;
            int space = BIN_CAP - binload[b];
            if (space <= 0) break;  // cannot happen: total tiles <= 80
            int take = (rem < space) ? rem : space;
            for (int i = 0; i < take; i++)
                tilemap[b * BIN_CAP + binload[b] + i] = make_int2(e, ti + i);
            binload[b] += take; ti += take; rem -= take;
        }
    }
}

__global__ __launch_bounds__(256) void k_scatter(const int* __restrict__ topi, int* __restrict__ cursors,
                                                 int* __restrict__ toklist, int* __restrict__ slotof) {
    int i = blockIdx.x * 256 + threadIdx.x;
    int e = topi[i];
    int s = atomicAdd(&cursors[e], 1);
    toklist[s] = i >> 1;
    slotof[i]  = s;
}

// ---------------- grouped expert GEMM: 128x128 tile, 2-phase double-buffered ----------------
// 4 waves each own a 64x64 sub-tile (4x4 16x16x32 bf16 frags).
// A/B staged via global_load_lds width=16, linear LDS dest, XOR-swizzled SOURCE
// chunk + matching swizzled ds_read (both-sides involution, rule #21).
// Pipeline: STAGE(buf^1, t+1) issued BEFORE compute(buf); single __syncthreads
// per K-step (its implicit vmcnt(0) drain is hidden under the 32 MFMAs).
// XCD chunking: tile-row y = (id%8)*BIN_CAP + ..., so each XCD owns a bin of
// tiles (bin-packed by expert in k_scan).
// MODE 0: gather x rows, relu -> bf16 h    (L1)
// MODE 1: contiguous h in, relu -> bf16 h  (L2)
// MODE 2: contiguous h in, fp32 out + bias (L3)
template <int KD, int ND, int MODE>
__global__ __launch_bounds__(256, 2) void k_expert_gemm(
    const unsigned short* __restrict__ Xin, const unsigned short* __restrict__ Wt,
    const float* __restrict__ bg, unsigned short* __restrict__ Hout,
    float* __restrict__ Oout, const int* __restrict__ counts,
    const int* __restrict__ offsets, const int* __restrict__ toklist,
    const int2* __restrict__ tilemap) {
    int id   = blockIdx.y * gridDim.x + blockIdx.x;   // dispatch-linear (x fast)
    int cxcd = id & 7;
    int jj   = id >> 3;
    int y    = cxcd * BIN_CAP + jj % BIN_CAP;
    int xnb  = jj / BIN_CAP;

    int2 tm = tilemap[y];
    int e = tm.x;
    if (e < 0) return;
    int mt  = tm.y;
    int n_e = counts[e];
    if (mt * 128 >= n_e) return;
    int off = offsets[e];
    int n0  = xnb * 128;

    // [row][64 k] bf16, linear (global_load_lds requires contiguous dest), x2 buffers
    __shared__ __align__(16) unsigned short As[2][128 * 64];
    __shared__ __align__(16) unsigned short Bs[2][128 * 64];

    int t    = threadIdx.x;
    int lane = t & 63;
    int w    = t >> 6;
    int wr   = (w >> 1) * 64;   // wave row origin
    int wc   = (w & 1) * 64;    // wave col origin

    // staging geometry: issue i covers rows i*32 + w*8 + (lane>>3); chunk = lane&7
    int srow = lane >> 3;
    int swz  = (lane & 7) ^ srow;   // source chunk, swizzled (row&7 == srow for every issue)
    const unsigned short* asrc[4];
    const unsigned short* bsrc[4];
#pragma unroll
    for (int i = 0; i < 4; i++) {
        int r = i * 32 + w * 8 + srow;
        int g = mt * 128 + r;
        size_t arow;
        if (MODE == 0) {
            int gg = (g < n_e) ? g : (n_e - 1);
            arow = (size_t)toklist[off + gg];
        } else {
            arow = (size_t)(off + g);   // may bleed into pad; masked at store
        }
        asrc[i] = Xin + arow * KD + swz * 8;
        bsrc[i] = Wt + ((size_t)e * ND + n0 + r) * KD + swz * 8;
    }

    auto STAGE = [&](int buf, int kt) {
#pragma unroll
        for (int i = 0; i < 4; i++) {
            gload16(asrc[i] + kt, &As[buf][(i * 32 + w * 8) * 64] + lane * 8);
            gload16(bsrc[i] + kt, &Bs[buf][(i * 32 + w * 8) * 64] + lane * 8);
        }
    };

    f32x4 acc[4][4];
#pragma unroll
    for (int mi = 0; mi < 4; mi++)
#pragma unroll
        for (int ni = 0; ni < 4; ni++) acc[mi][ni] = {0.f, 0.f, 0.f, 0.f};

    int lr  = lane & 15;
    int lkc = lane >> 4;          // 0..3: which 16B chunk of the 32-elem k-slice

    constexpr int T = KD / 64;
    STAGE(0, 0);
    __syncthreads();

    for (int tt = 0; tt < T; tt++) {
        int cur = tt & 1;
        if (tt + 1 < T) STAGE(cur ^ 1, (tt + 1) * 64);
        const char* Ab = (const char*)As[cur];
        const char* Bb = (const char*)Bs[cur];
#pragma unroll
        for (int ks = 0; ks < 2; ks++) {
            bf16x8 a[4], b[4];
#pragma unroll
            for (int mi = 0; mi < 4; mi++) {
                int row = wr + mi * 16 + lr;
                int c   = (lkc + ks * 4) ^ (row & 7);
                a[mi] = *reinterpret_cast<const bf16x8*>(Ab + row * 128 + c * 16);
            }
#pragma unroll
            for (int ni = 0; ni < 4; ni++) {
                int row = wc + ni * 16 + lr;
                int c   = (lkc + ks * 4) ^ (row & 7);
                b[ni] = *reinterpret_cast<const bf16x8*>(Bb + row * 128 + c * 16);
            }
#pragma unroll
            for (int mi = 0; mi < 4; mi++)
#pragma unroll
                for (int ni = 0; ni < 4; ni++)
                    acc[mi][ni] = __builtin_amdgcn_mfma_f32_16x16x32_bf16(a[mi], b[ni], acc[mi][ni], 0, 0, 0);
        }
        if (tt + 1 < T) __syncthreads();   // drains staging vmcnt + protects buf reuse
    }

    // epilogue: C/D map col=lane&15, row=(lane>>4)*4+reg
    int rowbase = (lane >> 4) * 4;
#pragma unroll
    for (int ni = 0; ni < 4; ni++) {
        int col = n0 + wc + ni * 16 + lr;
        float bv = bg[(size_t)e * ND + col];
#pragma unroll
        for (int mi = 0; mi < 4; mi++) {
#pragma unroll
            for (int qi = 0; qi < 4; qi++) {
                int g = mt * 128 + wr + mi * 16 + rowbase + qi;
                if (g < n_e) {
                    float v = acc[mi][ni][qi] + bv;
                    if (MODE == 2) {
                        Oout[(size_t)(off + g) * ND + col] = v;
                    } else {
                        v = fmaxf(v, 0.f);
                        Hout[(size_t)(off + g) * ND + col] = f2bf(v);
                    }
                }
            }
        }
    }
}

// ---------------- final combine (deterministic 2-term sum) ----------------
__global__ __launch_bounds__(128) void k_combine(const float* __restrict__ osl,
                                                 const float* __restrict__ gates,
                                                 const int* __restrict__ slotof,
                                                 float* __restrict__ outf) {
    int b = blockIdx.x;
    int j = threadIdx.x;
    int s0 = slotof[b * 2], s1 = slotof[b * 2 + 1];
    float g0 = gates[b * 2], g1 = gates[b * 2 + 1];
    float4 o0 = reinterpret_cast<const float4*>(osl + (size_t)s0 * OUTD)[j];
    float4 o1 = reinterpret_cast<const float4*>(osl + (size_t)s1 * OUTD)[j];
    float4 r;
    r.x = g0 * o0.x + g1 * o1.x;
    r.y = g0 * o0.y + g1 * o1.y;
    r.z = g0 * o0.z + g1 * o1.z;
    r.w = g0 * o0.w + g1 * o1.w;
    reinterpret_cast<float4*>(outf + (size_t)b * OUTD)[j] = r;
}

extern "C" void kernel_launch(void* const* d_in, const int* in_sizes, int n_in,
                              void* d_out, int out_size, void* d_ws, size_t ws_size,
                              hipStream_t stream) {
    const float* x   = (const float*)d_in[0];
    const float* Wr  = (const float*)d_in[1];
    const float* br  = (const float*)d_in[2];
    const float* emb = (const float*)d_in[3];
    const float* W1  = (const float*)d_in[4];
    const float* b1  = (const float*)d_in[5];
    const float* W2  = (const float*)d_in[6];
    const float* b2  = (const float*)d_in[7];
    const float* W3  = (const float*)d_in[8];
    const float* b3  = (const float*)d_in[9];

    float* out_final = (float*)d_out;
    float* out_q     = out_final + (size_t)BATCH * OUTD;
    float* out_gp    = out_q + (size_t)BATCH * EMB;

    char* ws = (char*)d_ws;
    unsigned short* xb  = (unsigned short*)(ws + WS_XB);
    unsigned short* h1  = (unsigned short*)(ws + WS_H1);
    unsigned short* h2  = (unsigned short*)(ws + WS_H2);
    float* osl    = (float*)(ws + WS_OSL);
    int*   topi   = (int*)(ws + WS_TOPI);
    float* gates  = (float*)(ws + WS_GATES);
    int*   slotof = (int*)(ws + WS_SLOTOF);
    int*   toklist= (int*)(ws + WS_TOKL);
    int*   counts = (int*)(ws + WS_CNT);
    int*   offsets= counts + 16;
    int*   cursors= counts + 32;
    int2*  tilemap= (int2*)(ws + WS_TMAP);
    unsigned short* wt = (unsigned short*)(ws + WS_WT);

    k_cvt_x<<<BATCH * D_IN / 4 / 256, 256, 0, stream>>>(x, xb);
    k_router_gemm<<<dim3(BATCH / 64, EMB / 64), 256, 0, stream>>>(x, Wr, br, out_q);
    k_router_topk<<<BATCH / 4, 256, 0, stream>>>(out_q, emb, out_gp, topi, gates);
    k_zero<<<1, 64, 0, stream>>>(counts);
    k_count<<<SLOTS / 256, 256, 0, stream>>>(topi, counts);
    k_scan<<<1, 64, 0, stream>>>(counts, offsets, cursors, tilemap);
    k_scatter<<<SLOTS / 256, 256, 0, stream>>>(topi, cursors, toklist, slotof);

    k_wtrans<<<dim3(H1 / 64, D_IN / 64, NEXP), 256, 0, stream>>>(W1, wt, D_IN, H1);
    k_expert_gemm<D_IN, H1, 0><<<dim3(H1 / 128, MAX_TILES), 256, 0, stream>>>(
        xb, wt, b1, h1, nullptr, counts, offsets, toklist, tilemap);

    k_wtrans<<<dim3(H2 / 64, H1 / 64, NEXP), 256, 0, stream>>>(W2, wt, H1, H2);
    k_expert_gemm<H1, H2, 1><<<dim3(H2 / 128, MAX_TILES), 256, 0, stream>>>(
        h1, wt, b2, h2, nullptr, counts, offsets, toklist, tilemap);

    k_wtrans<<<dim3(OUTD / 64, H2 / 64, NEXP), 256, 0, stream>>>(W3, wt, H2, OUTD);
    k_expert_gemm<H2, OUTD, 2><<<dim3(OUTD / 128, MAX_TILES), 256, 0, stream>>>(
        h2, wt, b3, nullptr, osl, counts, offsets, toklist, tilemap);

    k_combine<<<BATCH, 128, 0, stream>>>(osl, gates, slotof, out_final);
}